// Round 1
// baseline (301.886 us; speedup 1.0000x reference)
//
#include <hip/hip_runtime.h>
#include <cmath>
#include <cstring>

// SPD log via degree-11 polynomial approximation (Chebyshev on [0.5, 6.0]),
// evaluated with Paterson-Stockmeyer (s=3): 5 matmuls of 64x64x64 per matrix.
// Y = (A - m I)/r has spectrum in [-1,1]; p(Y) ~= log(A) elementwise to ~3e-4.

struct Coefs {
  float a[12];   // monomial coefficients in Y
  float m;       // center 3.25
  float invr;    // 1/2.75
};

__device__ __forceinline__ void mm64(const float (&Am)[64][64],
                                     const float (&Bm)[64][64],
                                     int r0, int c0, float (&acc)[4][4]) {
  // C[r][c] = sum_k Am[k][r]*Bm[k][c]  == (Am^T * Bm)[r][c]; Am symmetric -> Am*Bm.
  #pragma unroll
  for (int i = 0; i < 4; ++i)
    #pragma unroll
    for (int j = 0; j < 4; ++j) acc[i][j] = 0.f;
  #pragma unroll 8
  for (int k = 0; k < 64; ++k) {
    const float4 a4 = *(const float4*)&Am[k][r0];
    const float4 b4 = *(const float4*)&Bm[k][c0];
    const float av[4] = {a4.x, a4.y, a4.z, a4.w};
    const float bv[4] = {b4.x, b4.y, b4.z, b4.w};
    #pragma unroll
    for (int i = 0; i < 4; ++i)
      #pragma unroll
      for (int j = 0; j < 4; ++j)
        acc[i][j] = fmaf(av[i], bv[j], acc[i][j]);
  }
}

__device__ __forceinline__ void addB(float aI, float bY, float cP2,
                                     int r0, int c0,
                                     const float (&Ys)[64][64],
                                     const float (&P2s)[64][64],
                                     float (&acc)[4][4]) {
  #pragma unroll
  for (int i = 0; i < 4; ++i) {
    const float4 y4 = *(const float4*)&Ys[r0 + i][c0];
    const float4 p4 = *(const float4*)&P2s[r0 + i][c0];
    const float yv[4] = {y4.x, y4.y, y4.z, y4.w};
    const float pv[4] = {p4.x, p4.y, p4.z, p4.w};
    #pragma unroll
    for (int j = 0; j < 4; ++j) {
      float v = bY * yv[j] + cP2 * pv[j];
      if ((r0 + i) == (c0 + j)) v += aI;
      acc[i][j] += v;
    }
  }
}

__device__ __forceinline__ void storeT(float (&Dst)[64][64], int r0, int c0,
                                       const float (&acc)[4][4]) {
  #pragma unroll
  for (int i = 0; i < 4; ++i) {
    float4 v = make_float4(acc[i][0], acc[i][1], acc[i][2], acc[i][3]);
    *(float4*)&Dst[r0 + i][c0] = v;
  }
}

__global__ __launch_bounds__(256) void spdlog64(const float* __restrict__ A,
                                                float* __restrict__ O,
                                                Coefs cf) {
  __shared__ float Ys[64][64];
  __shared__ float P2s[64][64];
  __shared__ float P3s[64][64];
  __shared__ float Rs[64][64];
  __shared__ float Ts[64][64];

  const int b = blockIdx.x;
  const float* Ab = A + (size_t)b * 4096;
  float* Ob = O + (size_t)b * 4096;
  const int t = threadIdx.x;
  const int r0 = (t >> 4) << 2;   // 16 row-groups of 4
  const int c0 = (t & 15) << 2;   // 16 col-groups of 4

  // ---- load A (coalesced float4), form Y = (A - m I) * invr ----
  {
    const float4* src = (const float4*)Ab;
    float4* dst = (float4*)&Ys[0][0];
    #pragma unroll
    for (int i = 0; i < 4; ++i) {
      int q = t + 256 * i;            // float4 index 0..1023
      float4 v = src[q];
      int e = q << 2;
      int row = e >> 6;
      int col = e & 63;
      v.x = (v.x - ((col + 0) == row ? cf.m : 0.f)) * cf.invr;
      v.y = (v.y - ((col + 1) == row ? cf.m : 0.f)) * cf.invr;
      v.z = (v.z - ((col + 2) == row ? cf.m : 0.f)) * cf.invr;
      v.w = (v.w - ((col + 3) == row ? cf.m : 0.f)) * cf.invr;
      dst[q] = v;
    }
  }
  __syncthreads();

  float acc[4][4];

  // P2 = Y*Y
  mm64(Ys, Ys, r0, c0, acc);
  storeT(P2s, r0, c0, acc);
  __syncthreads();

  // P3 = Y*P2 ; also materialize T = B3 = a9 I + a10 Y + a11 P2
  mm64(Ys, P2s, r0, c0, acc);
  storeT(P3s, r0, c0, acc);
  #pragma unroll
  for (int i = 0; i < 4; ++i) {
    const float4 y4 = *(const float4*)&Ys[r0 + i][c0];
    const float4 p4 = *(const float4*)&P2s[r0 + i][c0];
    float4 o;
    o.x = cf.a[10] * y4.x + cf.a[11] * p4.x + ((r0 + i) == (c0 + 0) ? cf.a[9] : 0.f);
    o.y = cf.a[10] * y4.y + cf.a[11] * p4.y + ((r0 + i) == (c0 + 1) ? cf.a[9] : 0.f);
    o.z = cf.a[10] * y4.z + cf.a[11] * p4.z + ((r0 + i) == (c0 + 2) ? cf.a[9] : 0.f);
    o.w = cf.a[10] * y4.w + cf.a[11] * p4.w + ((r0 + i) == (c0 + 3) ? cf.a[9] : 0.f);
    *(float4*)&Ts[r0 + i][c0] = o;
  }
  __syncthreads();

  // R = P3*B3 + B2
  mm64(P3s, Ts, r0, c0, acc);
  addB(cf.a[6], cf.a[7], cf.a[8], r0, c0, Ys, P2s, acc);
  storeT(Rs, r0, c0, acc);
  __syncthreads();

  // T = P3*R + B1
  mm64(P3s, Rs, r0, c0, acc);
  addB(cf.a[3], cf.a[4], cf.a[5], r0, c0, Ys, P2s, acc);
  storeT(Ts, r0, c0, acc);
  __syncthreads();

  // out = P3*T + B0  -> straight to global
  mm64(P3s, Ts, r0, c0, acc);
  addB(cf.a[0], cf.a[1], cf.a[2], r0, c0, Ys, P2s, acc);
  #pragma unroll
  for (int i = 0; i < 4; ++i) {
    float4 v = make_float4(acc[i][0], acc[i][1], acc[i][2], acc[i][3]);
    *(float4*)&Ob[(size_t)(r0 + i) * 64 + c0] = v;
  }
}

extern "C" void kernel_launch(void* const* d_in, const int* in_sizes, int n_in,
                              void* d_out, int out_size, void* d_ws, size_t ws_size,
                              hipStream_t stream) {
  (void)n_in; (void)out_size; (void)d_ws; (void)ws_size;
  const float* A = (const float*)d_in[0];
  float* O = (float*)d_out;
  const int nb = in_sizes[0] / 4096;   // number of 64x64 matrices

  // --- Chebyshev coefficients of log(x) on [lo, hi], closed form ---
  // x = m(1 + rho t); log(1+rho t) = -log(1+z^2) + 2*sum_{k>=1} (-1)^{k+1} z^k/k T_k(t)
  // with z = (1 - sqrt(1-rho^2))/rho.
  const double lo = 0.5, hi = 6.0;
  const double m = 0.5 * (lo + hi), r = 0.5 * (hi - lo), rho = r / m;
  const double sq = std::sqrt(1.0 - rho * rho);
  const double z = (1.0 - sq) / rho;
  const int D = 11;
  double c[12];
  c[0] = std::log(m) - std::log1p(z * z);
  double zk = z;
  for (int k = 1; k <= D; ++k) {
    c[k] = 2.0 * ((k & 1) ? 1.0 : -1.0) * zk / (double)k;
    zk *= z;
  }
  // Chebyshev -> monomial (in t); intermediates bounded, done in double.
  double Tp[12] = {0}, Tc[12] = {0}, Tn[12];
  double am[12] = {0};
  Tp[0] = 1.0; am[0] += c[0] * Tp[0];
  Tc[1] = 1.0; am[1] += c[1] * Tc[1];
  for (int k = 2; k <= D; ++k) {
    for (int j = 0; j < 12; ++j) Tn[j] = (j ? 2.0 * Tc[j - 1] : 0.0) - Tp[j];
    for (int j = 0; j < 12; ++j) am[j] += c[k] * Tn[j];
    std::memcpy(Tp, Tc, sizeof Tp);
    std::memcpy(Tc, Tn, sizeof Tc);
  }
  Coefs cf;
  for (int j = 0; j < 12; ++j) cf.a[j] = (float)am[j];
  cf.m = (float)m;
  cf.invr = (float)(1.0 / r);

  spdlog64<<<nb, 256, 0, stream>>>(A, O, cf);
}

// Round 3
// 100.218 us; speedup vs baseline: 3.0123x; 3.0123x over previous
//
#include <hip/hip_runtime.h>
#include <cmath>
#include <cstring>

// SPD log(A) for 8192 64x64 SPD matrices.
// Degree-9 polynomial (Chebyshev on [0.5,6.5]) in Y=(A-mI)/r, Paterson-
// Stockmeyer with scalar top coefficient: 4 matmuls per matrix, all on MFMA
// (fp16 hi/lo split, 3x mfma_f32_16x16x32_f16 per product, fp32 accumulate).
// All intermediates are polynomials in Y => symmetric => A- and B-fragments
// both read as contiguous row slices from LDS; stores go back transposed.
// LDS planes XOR-swizzled to kill the 128B-stride bank conflict.

typedef _Float16 half8 __attribute__((ext_vector_type(8)));
typedef _Float16 half4 __attribute__((ext_vector_type(4)));
typedef __fp16 pk16x2 __attribute__((ext_vector_type(2)));  // cvt_pkrtz result type
typedef float f32x4 __attribute__((ext_vector_type(4)));

struct Coefs { float a[10]; float m, invr; };

// plane byte offsets inside the 64 KB LDS block
#define PL_YH  0
#define PL_YL  8192
#define PL_P2H 16384
#define PL_P2L 24576
#define PL_P3H 32768
#define PL_P3L 40960
#define PL_RH  49152
#define PL_RL  57344

__device__ __forceinline__ int swz(int row, int bytecol) {
  return row * 128 + (bytecol ^ ((row & 7) << 4));
}

__device__ __forceinline__ unsigned long long pack64(pk16x2 a, pk16x2 b) {
  return ((unsigned long long)__builtin_bit_cast(unsigned int, b) << 32) |
         (unsigned long long)__builtin_bit_cast(unsigned int, a);
}

// split 4 f32 into packed f16 hi (RTZ) and f16 lo (residual)
__device__ __forceinline__ void split4(const float* x, unsigned long long& hi,
                                       unsigned long long& lo) {
  pk16x2 h01 = __builtin_amdgcn_cvt_pkrtz(x[0], x[1]);
  pk16x2 h23 = __builtin_amdgcn_cvt_pkrtz(x[2], x[3]);
  float l0 = x[0] - (float)h01[0];
  float l1 = x[1] - (float)h01[1];
  float l2 = x[2] - (float)h23[0];
  float l3 = x[3] - (float)h23[1];
  pk16x2 q01 = __builtin_amdgcn_cvt_pkrtz(l0, l1);
  pk16x2 q23 = __builtin_amdgcn_cvt_pkrtz(l2, l3);
  hi = pack64(h01, h23);
  lo = pack64(q01, q23);
}

// fragment read: lane holds M[band*16 + (l&15)][32s + (l>>4)*8 .. +7]
// (valid for A directly; valid for B because all matrices are symmetric)
__device__ __forceinline__ half8 read_frag(const char* lds, int plane,
                                           int band, int s, int lane) {
  int row = band * 16 + (lane & 15);
  int bc = s * 64 + ((lane >> 4) << 4);
  return *(const half8*)(lds + plane + swz(row, bc));
}

// C(rows 16w..16w+15, all 64 cols) = A * B, hi/lo split => 3 MFMAs/fragment
__device__ __forceinline__ void mm(const char* lds, int ah, int al, int bh,
                                   int bl, int w, int lane, f32x4 acc[4]) {
  #pragma unroll
  for (int s = 0; s < 2; ++s) {
    half8 Ah = read_frag(lds, ah, w, s, lane);
    half8 Al = read_frag(lds, al, w, s, lane);
    #pragma unroll
    for (int f = 0; f < 4; ++f) {
      half8 Bh = read_frag(lds, bh, f, s, lane);
      half8 Bl = read_frag(lds, bl, f, s, lane);
      acc[f] = __builtin_amdgcn_mfma_f32_16x16x32_f16(Ah, Bh, acc[f], 0, 0, 0);
      acc[f] = __builtin_amdgcn_mfma_f32_16x16x32_f16(Ah, Bl, acc[f], 0, 0, 0);
      acc[f] = __builtin_amdgcn_mfma_f32_16x16x32_f16(Al, Bh, acc[f], 0, 0, 0);
    }
  }
}

// store acc transposed (result symmetric): plane[c][r0..r0+3] packed b64
__device__ __forceinline__ void store_acc(char* lds, int ph, int pl, int w,
                                          int lane, const f32x4 acc[4]) {
  int r0 = w * 16 + ((lane >> 4) << 2);
  #pragma unroll
  for (int f = 0; f < 4; ++f) {
    int c = f * 16 + (lane & 15);
    float x[4] = {acc[f][0], acc[f][1], acc[f][2], acc[f][3]};
    unsigned long long hi, lo;
    split4(x, hi, lo);
    int off = swz(c, r0 * 2);
    *(unsigned long long*)(lds + ph + off) = hi;
    *(unsigned long long*)(lds + pl + off) = lo;
  }
}

// acc += aI*I + aY*Y + aP2*P2 (read transposed via symmetry)
__device__ __forceinline__ void epi(const char* lds, float aI, float aY,
                                    float aP2, int w, int lane, f32x4 acc[4]) {
  int r0 = w * 16 + ((lane >> 4) << 2);
  #pragma unroll
  for (int f = 0; f < 4; ++f) {
    int c = f * 16 + (lane & 15);
    int off = swz(c, r0 * 2);
    half4 yh = *(const half4*)(lds + PL_YH + off);
    half4 yl = *(const half4*)(lds + PL_YL + off);
    half4 ph = *(const half4*)(lds + PL_P2H + off);
    half4 pl = *(const half4*)(lds + PL_P2L + off);
    #pragma unroll
    for (int j = 0; j < 4; ++j) {
      float y = (float)yh[j] + (float)yl[j];
      float p = (float)ph[j] + (float)pl[j];
      float v = aY * y + aP2 * p;
      if (r0 + j == c) v += aI;
      acc[f][j] += v;
    }
  }
}

__global__ __launch_bounds__(256) void spdlog64(const float* __restrict__ A,
                                                float* __restrict__ O,
                                                Coefs cf) {
  __shared__ __align__(16) char lds[65536];
  const int b = blockIdx.x;
  const float* Ab = A + (size_t)b * 4096;
  float* Ob = O + (size_t)b * 4096;
  const int t = threadIdx.x;
  const int lane = t & 63;
  const int w = t >> 6;

  // ---- build Y = (A - m I) * invr, split to f16 hi/lo planes ----
  #pragma unroll
  for (int i = 0; i < 4; ++i) {
    int q = t + 256 * i;                     // float4 index 0..1023
    float4 v = ((const float4*)Ab)[q];
    int e = q << 2, row = e >> 6, col = e & 63;
    float x[4];
    x[0] = (v.x - (col + 0 == row ? cf.m : 0.f)) * cf.invr;
    x[1] = (v.y - (col + 1 == row ? cf.m : 0.f)) * cf.invr;
    x[2] = (v.z - (col + 2 == row ? cf.m : 0.f)) * cf.invr;
    x[3] = (v.w - (col + 3 == row ? cf.m : 0.f)) * cf.invr;
    unsigned long long hi, lo;
    split4(x, hi, lo);
    int off = swz(row, col * 2);
    *(unsigned long long*)(lds + PL_YH + off) = hi;
    *(unsigned long long*)(lds + PL_YL + off) = lo;
  }
  __syncthreads();

  f32x4 acc[4];

  // ---- P2 = Y*Y ----
  #pragma unroll
  for (int f = 0; f < 4; ++f) acc[f] = (f32x4)0.f;
  mm(lds, PL_YH, PL_YL, PL_YH, PL_YL, w, lane, acc);
  store_acc(lds, PL_P2H, PL_P2L, w, lane, acc);
  __syncthreads();

  // ---- P3 = Y*P2 ----
  #pragma unroll
  for (int f = 0; f < 4; ++f) acc[f] = (f32x4)0.f;
  mm(lds, PL_YH, PL_YL, PL_P2H, PL_P2L, w, lane, acc);
  store_acc(lds, PL_P3H, PL_P3L, w, lane, acc);
  __syncthreads();

  // ---- R1 = a9*P3 + a6*I + a7*Y + a8*P2 (elementwise) ----
  {
    int row = t >> 2;
    int cbase = (t & 3) * 16;
    #pragma unroll
    for (int ch = 0; ch < 2; ++ch) {
      int c = cbase + ch * 8;
      int off = swz(row, c * 2);
      half8 p3h = *(const half8*)(lds + PL_P3H + off);
      half8 p3l = *(const half8*)(lds + PL_P3L + off);
      half8 yh = *(const half8*)(lds + PL_YH + off);
      half8 yl = *(const half8*)(lds + PL_YL + off);
      half8 p2h = *(const half8*)(lds + PL_P2H + off);
      half8 p2l = *(const half8*)(lds + PL_P2L + off);
      float x[8];
      #pragma unroll
      for (int j = 0; j < 8; ++j) {
        float p3 = (float)p3h[j] + (float)p3l[j];
        float y = (float)yh[j] + (float)yl[j];
        float p2 = (float)p2h[j] + (float)p2l[j];
        float v = cf.a[9] * p3 + cf.a[7] * y + cf.a[8] * p2;
        if (row == c + j) v += cf.a[6];
        x[j] = v;
      }
      unsigned long long h0, l0, h1, l1;
      split4(x, h0, l0);
      split4(x + 4, h1, l1);
      *(unsigned long long*)(lds + PL_RH + off) = h0;
      *(unsigned long long*)(lds + PL_RH + off + 8) = h1;
      *(unsigned long long*)(lds + PL_RL + off) = l0;
      *(unsigned long long*)(lds + PL_RL + off + 8) = l1;
    }
  }
  __syncthreads();

  // ---- R2 = R1*P3 + (a3 I + a4 Y + a5 P2) ----
  #pragma unroll
  for (int f = 0; f < 4; ++f) acc[f] = (f32x4)0.f;
  mm(lds, PL_RH, PL_RL, PL_P3H, PL_P3L, w, lane, acc);
  epi(lds, cf.a[3], cf.a[4], cf.a[5], w, lane, acc);
  __syncthreads();  // all reads of R1 done before overwrite
  store_acc(lds, PL_RH, PL_RL, w, lane, acc);
  __syncthreads();

  // ---- out = R2*P3 + (a0 I + a1 Y + a2 P2) ----
  #pragma unroll
  for (int f = 0; f < 4; ++f) acc[f] = (f32x4)0.f;
  mm(lds, PL_RH, PL_RL, PL_P3H, PL_P3L, w, lane, acc);
  epi(lds, cf.a[0], cf.a[1], cf.a[2], w, lane, acc);

  // store transposed (symmetric): O[c][r0..r0+3] as float4
  {
    int r0 = w * 16 + ((lane >> 4) << 2);
    #pragma unroll
    for (int f = 0; f < 4; ++f) {
      int c = f * 16 + (lane & 15);
      float4 v = make_float4(acc[f][0], acc[f][1], acc[f][2], acc[f][3]);
      *(float4*)(Ob + c * 64 + r0) = v;
    }
  }
}

extern "C" void kernel_launch(void* const* d_in, const int* in_sizes, int n_in,
                              void* d_out, int out_size, void* d_ws, size_t ws_size,
                              hipStream_t stream) {
  (void)n_in; (void)out_size; (void)d_ws; (void)ws_size;
  const float* A = (const float*)d_in[0];
  float* O = (float*)d_out;
  const int nb = in_sizes[0] / 4096;

  // Chebyshev series of log(x) on [lo,hi], degree 9, closed form:
  // x = m(1 + rho t); log = (log m - log(1+z^2)) + 2*sum (-1)^{k+1} z^k/k T_k(t)
  const double lo = 0.5, hi = 6.5;
  const double m = 0.5 * (lo + hi), r = 0.5 * (hi - lo), rho = r / m;
  const double sq = std::sqrt(1.0 - rho * rho);
  const double z = (1.0 - sq) / rho;
  const int D = 9;
  double c[10];
  c[0] = std::log(m) - std::log1p(z * z);
  double zk = z;
  for (int k = 1; k <= D; ++k) {
    c[k] = 2.0 * ((k & 1) ? 1.0 : -1.0) * zk / (double)k;
    zk *= z;
  }
  // Chebyshev -> monomial in t
  double Tp[10] = {0}, Tc[10] = {0}, Tn[10];
  double am[10] = {0};
  Tp[0] = 1.0;
  am[0] += c[0];
  Tc[1] = 1.0;
  am[1] += c[1];
  for (int k = 2; k <= D; ++k) {
    for (int j = 0; j < 10; ++j) Tn[j] = (j ? 2.0 * Tc[j - 1] : 0.0) - Tp[j];
    for (int j = 0; j < 10; ++j) am[j] += c[k] * Tn[j];
    std::memcpy(Tp, Tc, sizeof Tp);
    std::memcpy(Tc, Tn, sizeof Tc);
  }
  Coefs cf;
  for (int j = 0; j < 10; ++j) cf.a[j] = (float)am[j];
  cf.m = (float)m;
  cf.invr = (float)(1.0 / r);

  spdlog64<<<nb, 256, 0, stream>>>(A, O, cf);
}

// Round 4
// 63.307 us; speedup vs baseline: 4.7686x; 1.5830x over previous
//
#include <hip/hip_runtime.h>
#include <cmath>
#include <cstring>

// SPD log(A), 8192 64x64 SPD matrices.
// Degree-9 Chebyshev poly on [0.5,6.0] in Y=(A-mI)/r, Paterson-Stockmeyer:
//   P2=Y*Y, P3=Y*P2, R1=a9*P3+B2 (elementwise), R2=P3*R1+B1, out=P3*R2+B0.
// Mixed precision: Y kept as f16 hi+lo (split product: 3 MFMA for P2, 2 for
// P3); P2/P3/R stored single f16 (storage err ~2e-4, O(1) sensitivity);
// epilogues in f32; RTNE conversions everywhere (no RTZ bias).
// LDS 40KB -> 4 blocks/CU. All matrices are polynomials in Y => symmetric =>
// A- and B-fragments both read as row slices; product stores go transposed.

typedef _Float16 half8 __attribute__((ext_vector_type(8)));
typedef _Float16 half4 __attribute__((ext_vector_type(4)));
typedef float f32x4 __attribute__((ext_vector_type(4)));

struct Coefs { float a[10]; float m, invr; };

#define PL_YH 0
#define PL_YL 8192
#define PL_P2 16384
#define PL_P3 24576
#define PL_R  32768
#define LDS_BYTES 40960

__device__ __forceinline__ int swz(int row, int bytecol) {
  return row * 128 + (bytecol ^ ((row & 7) << 4));
}

__device__ __forceinline__ half8 read_frag(const char* lds, int plane,
                                           int band, int s, int lane) {
  int row = band * 16 + (lane & 15);
  int bc = s * 64 + ((lane >> 4) << 4);
  return *(const half8*)(lds + plane + swz(row, bc));
}

#define MFMA16(a, b, c) __builtin_amdgcn_mfma_f32_16x16x32_f16((a), (b), (c), 0, 0, 0)

// acc += Y*Y (Y split hi/lo: 3 MFMA per fragment pair)
__device__ __forceinline__ void mmYY(const char* lds, int w, int lane,
                                     f32x4 acc[4]) {
  #pragma unroll
  for (int s = 0; s < 2; ++s) {
    half8 Ah = read_frag(lds, PL_YH, w, s, lane);
    half8 Al = read_frag(lds, PL_YL, w, s, lane);
    #pragma unroll
    for (int f = 0; f < 4; ++f) {
      half8 Bh = read_frag(lds, PL_YH, f, s, lane);
      half8 Bl = read_frag(lds, PL_YL, f, s, lane);
      acc[f] = MFMA16(Ah, Bh, acc[f]);
      acc[f] = MFMA16(Ah, Bl, acc[f]);
      acc[f] = MFMA16(Al, Bh, acc[f]);
    }
  }
}

// acc += Y*B (Y split, B single plane: 2 MFMA)
__device__ __forceinline__ void mmYS(const char* lds, int pb, int w, int lane,
                                     f32x4 acc[4]) {
  #pragma unroll
  for (int s = 0; s < 2; ++s) {
    half8 Ah = read_frag(lds, PL_YH, w, s, lane);
    half8 Al = read_frag(lds, PL_YL, w, s, lane);
    #pragma unroll
    for (int f = 0; f < 4; ++f) {
      half8 B = read_frag(lds, pb, f, s, lane);
      acc[f] = MFMA16(Ah, B, acc[f]);
      acc[f] = MFMA16(Al, B, acc[f]);
    }
  }
}

// acc += A*B (both single plane: 1 MFMA)
__device__ __forceinline__ void mmSS(const char* lds, int pa, int pb, int w,
                                     int lane, f32x4 acc[4]) {
  #pragma unroll
  for (int s = 0; s < 2; ++s) {
    half8 A = read_frag(lds, pa, w, s, lane);
    #pragma unroll
    for (int f = 0; f < 4; ++f) {
      half8 B = read_frag(lds, pb, f, s, lane);
      acc[f] = MFMA16(A, B, acc[f]);
    }
  }
}

// store acc transposed (result symmetric) as f16 (RTNE): plane[c][r0..r0+3]
__device__ __forceinline__ void store16(char* lds, int plane, int w, int lane,
                                        const f32x4 acc[4]) {
  int r0 = w * 16 + ((lane >> 4) << 2);
  #pragma unroll
  for (int f = 0; f < 4; ++f) {
    int c = f * 16 + (lane & 15);
    half4 h = {(_Float16)acc[f][0], (_Float16)acc[f][1],
               (_Float16)acc[f][2], (_Float16)acc[f][3]};
    *(half4*)(lds + plane + swz(c, r0 * 2)) = h;
  }
}

// acc += aI*I + aY*YH + aP2*P2 (read transposed via symmetry), f32 math
__device__ __forceinline__ void epi(const char* lds, float aI, float aY,
                                    float aP2, int w, int lane, f32x4 acc[4]) {
  int r0 = w * 16 + ((lane >> 4) << 2);
  #pragma unroll
  for (int f = 0; f < 4; ++f) {
    int c = f * 16 + (lane & 15);
    int off = swz(c, r0 * 2);
    half4 y = *(const half4*)(lds + PL_YH + off);
    half4 p = *(const half4*)(lds + PL_P2 + off);
    #pragma unroll
    for (int j = 0; j < 4; ++j) {
      float v = aY * (float)y[j] + aP2 * (float)p[j];
      if (r0 + j == c) v += aI;
      acc[f][j] += v;
    }
  }
}

__global__ __launch_bounds__(256) void spdlog64(const float* __restrict__ A,
                                                float* __restrict__ O,
                                                Coefs cf) {
  __shared__ __align__(16) char lds[LDS_BYTES];
  const int b = blockIdx.x;
  const float* Ab = A + (size_t)b * 4096;
  float* Ob = O + (size_t)b * 4096;
  const int t = threadIdx.x;
  const int lane = t & 63;
  const int w = t >> 6;

  // ---- load A, form Y = (A - m I)*invr, split f16 hi (RTNE) + residual ----
  #pragma unroll
  for (int i = 0; i < 4; ++i) {
    int q = t + 256 * i;                  // float4 index 0..1023
    float4 v = ((const float4*)Ab)[q];
    int e = q << 2, row = e >> 6, col = e & 63;
    float x[4];
    x[0] = (v.x - (col + 0 == row ? cf.m : 0.f)) * cf.invr;
    x[1] = (v.y - (col + 1 == row ? cf.m : 0.f)) * cf.invr;
    x[2] = (v.z - (col + 2 == row ? cf.m : 0.f)) * cf.invr;
    x[3] = (v.w - (col + 3 == row ? cf.m : 0.f)) * cf.invr;
    half4 h, l;
    #pragma unroll
    for (int j = 0; j < 4; ++j) {
      h[j] = (_Float16)x[j];
      l[j] = (_Float16)(x[j] - (float)h[j]);
    }
    int off = swz(row, col * 2);
    *(half4*)(lds + PL_YH + off) = h;
    *(half4*)(lds + PL_YL + off) = l;
  }
  __syncthreads();

  f32x4 acc[4];

  // ---- P2 = Y*Y ----
  #pragma unroll
  for (int f = 0; f < 4; ++f) acc[f] = (f32x4)0.f;
  mmYY(lds, w, lane, acc);
  store16(lds, PL_P2, w, lane, acc);
  __syncthreads();

  // ---- P3 = Y*P2 ----
  #pragma unroll
  for (int f = 0; f < 4; ++f) acc[f] = (f32x4)0.f;
  mmYS(lds, PL_P2, w, lane, acc);
  store16(lds, PL_P3, w, lane, acc);
  __syncthreads();

  // ---- R1 = a9*P3 + a6*I + a7*Y + a8*P2 (elementwise, f32 math) ----
  {
    int row = t >> 2;
    #pragma unroll
    for (int ch = 0; ch < 2; ++ch) {
      int c = (t & 3) * 16 + ch * 8;
      int off = swz(row, c * 2);
      half8 p3 = *(const half8*)(lds + PL_P3 + off);
      half8 y = *(const half8*)(lds + PL_YH + off);
      half8 p2 = *(const half8*)(lds + PL_P2 + off);
      half8 r;
      #pragma unroll
      for (int j = 0; j < 8; ++j) {
        float v = cf.a[9] * (float)p3[j] + cf.a[7] * (float)y[j] +
                  cf.a[8] * (float)p2[j];
        if (row == c + j) v += cf.a[6];
        r[j] = (_Float16)v;
      }
      *(half8*)(lds + PL_R + off) = r;
    }
  }
  __syncthreads();

  // ---- R2 = P3*R1 + (a3 I + a4 Y + a5 P2) ----
  #pragma unroll
  for (int f = 0; f < 4; ++f) acc[f] = (f32x4)0.f;
  mmSS(lds, PL_P3, PL_R, w, lane, acc);
  epi(lds, cf.a[3], cf.a[4], cf.a[5], w, lane, acc);
  __syncthreads();              // all reads of R1 done before overwrite
  store16(lds, PL_R, w, lane, acc);
  __syncthreads();

  // ---- out = P3*R2 + (a0 I + a1 Y + a2 P2) ----
  #pragma unroll
  for (int f = 0; f < 4; ++f) acc[f] = (f32x4)0.f;
  mmSS(lds, PL_P3, PL_R, w, lane, acc);
  epi(lds, cf.a[0], cf.a[1], cf.a[2], w, lane, acc);

  // store transposed (symmetric): O[c][r0..r0+3] as float4
  {
    int r0 = w * 16 + ((lane >> 4) << 2);
    #pragma unroll
    for (int f = 0; f < 4; ++f) {
      int c = f * 16 + (lane & 15);
      float4 v = make_float4(acc[f][0], acc[f][1], acc[f][2], acc[f][3]);
      *(float4*)(Ob + c * 64 + r0) = v;
    }
  }
}

extern "C" void kernel_launch(void* const* d_in, const int* in_sizes, int n_in,
                              void* d_out, int out_size, void* d_ws, size_t ws_size,
                              hipStream_t stream) {
  (void)n_in; (void)out_size; (void)d_ws; (void)ws_size;
  const float* A = (const float*)d_in[0];
  float* O = (float*)d_out;
  const int nb = in_sizes[0] / 4096;

  // Chebyshev series of log(x) on [lo,hi], degree 9, closed form:
  // x = m(1 + rho t); log = (log m - log(1+z^2)) + 2*sum (-1)^{k+1} z^k/k T_k(t)
  const double lo = 0.5, hi = 6.0;
  const double m = 0.5 * (lo + hi), r = 0.5 * (hi - lo), rho = r / m;
  const double sq = std::sqrt(1.0 - rho * rho);
  const double z = (1.0 - sq) / rho;
  const int D = 9;
  double c[10];
  c[0] = std::log(m) - std::log1p(z * z);
  double zk = z;
  for (int k = 1; k <= D; ++k) {
    c[k] = 2.0 * ((k & 1) ? 1.0 : -1.0) * zk / (double)k;
    zk *= z;
  }
  // Chebyshev -> monomial in t
  double Tp[10] = {0}, Tc[10] = {0}, Tn[10];
  double am[10] = {0};
  Tp[0] = 1.0;
  am[0] += c[0];
  Tc[1] = 1.0;
  am[1] += c[1];
  for (int k = 2; k <= D; ++k) {
    for (int j = 0; j < 10; ++j) Tn[j] = (j ? 2.0 * Tc[j - 1] : 0.0) - Tp[j];
    for (int j = 0; j < 10; ++j) am[j] += c[k] * Tn[j];
    std::memcpy(Tp, Tc, sizeof Tp);
    std::memcpy(Tc, Tn, sizeof Tc);
  }
  Coefs cf;
  for (int j = 0; j < 10; ++j) cf.a[j] = (float)am[j];
  cf.m = (float)m;
  cf.invr = (float)(1.0 / r);

  spdlog64<<<nb, 256, 0, stream>>>(A, O, cf);
}

// Round 5
// 62.218 us; speedup vs baseline: 4.8521x; 1.0175x over previous
//
#include <hip/hip_runtime.h>
#include <cmath>
#include <cstring>

// SPD log(A), 8192 64x64 SPD matrices.
// Degree-9 Chebyshev poly on [0.5,6.0] in Y=(A-mI)/r, Paterson-Stockmeyer:
//   P2=Y*Y, P3=Y*P2, R1=a9*P3+B2, R2=P3*R1+B1, out=P3*R2+B0.
// Mixed precision: Y kept as f16 hi+lo (3 MFMA for P2, 2 for P3); P2/P3/R
// single f16; epilogues f32; RTNE everywhere.
// Round 5: R1 fused into P3's store (one pass, reads P3 from f32 acc);
// R2 reuses the YL plane (dead after P3) -> barrier count 6 -> 4.
// Planes (40KB, 4 blocks/CU): YH | YL(->R2) | P2 | P3 | R1.
// All matrices are polynomials in Y => symmetric => A- and B-fragments both
// read as row slices; product stores go transposed. XOR-swizzled LDS.

typedef _Float16 half8 __attribute__((ext_vector_type(8)));
typedef _Float16 half4 __attribute__((ext_vector_type(4)));
typedef float f32x4 __attribute__((ext_vector_type(4)));

struct Coefs { float a[10]; float m, invr; };

#define PL_YH 0
#define PL_YL 8192
#define PL_P2 16384
#define PL_P3 24576
#define PL_R  32768
#define LDS_BYTES 40960

__device__ __forceinline__ int swz(int row, int bytecol) {
  return row * 128 + (bytecol ^ ((row & 7) << 4));
}

__device__ __forceinline__ half8 read_frag(const char* lds, int plane,
                                           int band, int s, int lane) {
  int row = band * 16 + (lane & 15);
  int bc = s * 64 + ((lane >> 4) << 4);
  return *(const half8*)(lds + plane + swz(row, bc));
}

#define MFMA16(a, b, c) __builtin_amdgcn_mfma_f32_16x16x32_f16((a), (b), (c), 0, 0, 0)

// acc += Y*Y (Y split hi/lo: 3 MFMA per fragment pair)
__device__ __forceinline__ void mmYY(const char* lds, int w, int lane,
                                     f32x4 acc[4]) {
  #pragma unroll
  for (int s = 0; s < 2; ++s) {
    half8 Ah = read_frag(lds, PL_YH, w, s, lane);
    half8 Al = read_frag(lds, PL_YL, w, s, lane);
    #pragma unroll
    for (int f = 0; f < 4; ++f) {
      half8 Bh = read_frag(lds, PL_YH, f, s, lane);
      half8 Bl = read_frag(lds, PL_YL, f, s, lane);
      acc[f] = MFMA16(Ah, Bh, acc[f]);
      acc[f] = MFMA16(Ah, Bl, acc[f]);
      acc[f] = MFMA16(Al, Bh, acc[f]);
    }
  }
}

// acc += Y*B (Y split, B single plane: 2 MFMA)
__device__ __forceinline__ void mmYS(const char* lds, int pb, int w, int lane,
                                     f32x4 acc[4]) {
  #pragma unroll
  for (int s = 0; s < 2; ++s) {
    half8 Ah = read_frag(lds, PL_YH, w, s, lane);
    half8 Al = read_frag(lds, PL_YL, w, s, lane);
    #pragma unroll
    for (int f = 0; f < 4; ++f) {
      half8 B = read_frag(lds, pb, f, s, lane);
      acc[f] = MFMA16(Ah, B, acc[f]);
      acc[f] = MFMA16(Al, B, acc[f]);
    }
  }
}

// acc += A*B (both single plane: 1 MFMA)
__device__ __forceinline__ void mmSS(const char* lds, int pa, int pb, int w,
                                     int lane, f32x4 acc[4]) {
  #pragma unroll
  for (int s = 0; s < 2; ++s) {
    half8 A = read_frag(lds, pa, w, s, lane);
    #pragma unroll
    for (int f = 0; f < 4; ++f) {
      half8 B = read_frag(lds, pb, f, s, lane);
      acc[f] = MFMA16(A, B, acc[f]);
    }
  }
}

// store acc transposed (result symmetric) as f16 (RTNE): plane[c][r0..r0+3]
__device__ __forceinline__ void store16(char* lds, int plane, int w, int lane,
                                        const f32x4 acc[4]) {
  int r0 = w * 16 + ((lane >> 4) << 2);
  #pragma unroll
  for (int f = 0; f < 4; ++f) {
    int c = f * 16 + (lane & 15);
    half4 h = {(_Float16)acc[f][0], (_Float16)acc[f][1],
               (_Float16)acc[f][2], (_Float16)acc[f][3]};
    *(half4*)(lds + plane + swz(c, r0 * 2)) = h;
  }
}

// fused: store P3 (=acc) and R1 = a9*acc + a6 I + a7 Y + a8 P2, both
// transposed; Y/P2 read at the transposed spot (valid: all symmetric).
__device__ __forceinline__ void storeP3R1(char* lds, const Coefs& cf, int w,
                                          int lane, const f32x4 acc[4]) {
  int r0 = w * 16 + ((lane >> 4) << 2);
  #pragma unroll
  for (int f = 0; f < 4; ++f) {
    int c = f * 16 + (lane & 15);
    int off = swz(c, r0 * 2);
    half4 p3 = {(_Float16)acc[f][0], (_Float16)acc[f][1],
                (_Float16)acc[f][2], (_Float16)acc[f][3]};
    *(half4*)(lds + PL_P3 + off) = p3;
    half4 y = *(const half4*)(lds + PL_YH + off);
    half4 p2 = *(const half4*)(lds + PL_P2 + off);
    half4 r;
    #pragma unroll
    for (int j = 0; j < 4; ++j) {
      float v = cf.a[9] * acc[f][j] + cf.a[7] * (float)y[j] +
                cf.a[8] * (float)p2[j];
      if (r0 + j == c) v += cf.a[6];
      r[j] = (_Float16)v;
    }
    *(half4*)(lds + PL_R + off) = r;
  }
}

// acc += aI*I + aY*YH + aP2*P2 (read transposed via symmetry), f32 math
__device__ __forceinline__ void epi(const char* lds, float aI, float aY,
                                    float aP2, int w, int lane, f32x4 acc[4]) {
  int r0 = w * 16 + ((lane >> 4) << 2);
  #pragma unroll
  for (int f = 0; f < 4; ++f) {
    int c = f * 16 + (lane & 15);
    int off = swz(c, r0 * 2);
    half4 y = *(const half4*)(lds + PL_YH + off);
    half4 p = *(const half4*)(lds + PL_P2 + off);
    #pragma unroll
    for (int j = 0; j < 4; ++j) {
      float v = aY * (float)y[j] + aP2 * (float)p[j];
      if (r0 + j == c) v += aI;
      acc[f][j] += v;
    }
  }
}

__global__ __launch_bounds__(256) void spdlog64(const float* __restrict__ A,
                                                float* __restrict__ O,
                                                Coefs cf) {
  __shared__ __align__(16) char lds[LDS_BYTES];
  const int b = blockIdx.x;
  const float* Ab = A + (size_t)b * 4096;
  float* Ob = O + (size_t)b * 4096;
  const int t = threadIdx.x;
  const int lane = t & 63;
  const int w = t >> 6;

  // ---- load A, form Y = (A - m I)*invr, split f16 hi (RTNE) + residual ----
  #pragma unroll
  for (int i = 0; i < 4; ++i) {
    int q = t + 256 * i;                  // float4 index 0..1023
    float4 v = ((const float4*)Ab)[q];
    int e = q << 2, row = e >> 6, col = e & 63;
    float x[4];
    x[0] = (v.x - (col + 0 == row ? cf.m : 0.f)) * cf.invr;
    x[1] = (v.y - (col + 1 == row ? cf.m : 0.f)) * cf.invr;
    x[2] = (v.z - (col + 2 == row ? cf.m : 0.f)) * cf.invr;
    x[3] = (v.w - (col + 3 == row ? cf.m : 0.f)) * cf.invr;
    half4 h, l;
    #pragma unroll
    for (int j = 0; j < 4; ++j) {
      h[j] = (_Float16)x[j];
      l[j] = (_Float16)(x[j] - (float)h[j]);
    }
    int off = swz(row, col * 2);
    *(half4*)(lds + PL_YH + off) = h;
    *(half4*)(lds + PL_YL + off) = l;
  }
  __syncthreads();                        // barrier 1

  f32x4 acc[4];

  // ---- P2 = Y*Y ----
  #pragma unroll
  for (int f = 0; f < 4; ++f) acc[f] = (f32x4)0.f;
  mmYY(lds, w, lane, acc);
  store16(lds, PL_P2, w, lane, acc);
  __syncthreads();                        // barrier 2

  // ---- P3 = Y*P2, fused R1 = a9*P3 + a6 I + a7 Y + a8 P2 ----
  #pragma unroll
  for (int f = 0; f < 4; ++f) acc[f] = (f32x4)0.f;
  mmYS(lds, PL_P2, w, lane, acc);
  storeP3R1(lds, cf, w, lane, acc);
  __syncthreads();                        // barrier 3

  // ---- R2 = P3*R1 + (a3 I + a4 Y + a5 P2)  -> stored into YL (dead) ----
  #pragma unroll
  for (int f = 0; f < 4; ++f) acc[f] = (f32x4)0.f;
  mmSS(lds, PL_P3, PL_R, w, lane, acc);
  epi(lds, cf.a[3], cf.a[4], cf.a[5], w, lane, acc);
  store16(lds, PL_YL, w, lane, acc);
  __syncthreads();                        // barrier 4

  // ---- out = P3*R2 + (a0 I + a1 Y + a2 P2) ----
  #pragma unroll
  for (int f = 0; f < 4; ++f) acc[f] = (f32x4)0.f;
  mmSS(lds, PL_P3, PL_YL, w, lane, acc);
  epi(lds, cf.a[0], cf.a[1], cf.a[2], w, lane, acc);

  // store transposed (symmetric): O[c][r0..r0+3] as float4
  {
    int r0 = w * 16 + ((lane >> 4) << 2);
    #pragma unroll
    for (int f = 0; f < 4; ++f) {
      int c = f * 16 + (lane & 15);
      float4 v = make_float4(acc[f][0], acc[f][1], acc[f][2], acc[f][3]);
      *(float4*)(Ob + c * 64 + r0) = v;
    }
  }
}

extern "C" void kernel_launch(void* const* d_in, const int* in_sizes, int n_in,
                              void* d_out, int out_size, void* d_ws, size_t ws_size,
                              hipStream_t stream) {
  (void)n_in; (void)out_size; (void)d_ws; (void)ws_size;
  const float* A = (const float*)d_in[0];
  float* O = (float*)d_out;
  const int nb = in_sizes[0] / 4096;

  // Chebyshev series of log(x) on [lo,hi], degree 9, closed form:
  // x = m(1 + rho t); log = (log m - log(1+z^2)) + 2*sum (-1)^{k+1} z^k/k T_k(t)
  const double lo = 0.5, hi = 6.0;
  const double m = 0.5 * (lo + hi), r = 0.5 * (hi - lo), rho = r / m;
  const double sq = std::sqrt(1.0 - rho * rho);
  const double z = (1.0 - sq) / rho;
  const int D = 9;
  double c[10];
  c[0] = std::log(m) - std::log1p(z * z);
  double zk = z;
  for (int k = 1; k <= D; ++k) {
    c[k] = 2.0 * ((k & 1) ? 1.0 : -1.0) * zk / (double)k;
    zk *= z;
  }
  // Chebyshev -> monomial in t
  double Tp[10] = {0}, Tc[10] = {0}, Tn[10];
  double am[10] = {0};
  Tp[0] = 1.0;
  am[0] += c[0];
  Tc[1] = 1.0;
  am[1] += c[1];
  for (int k = 2; k <= D; ++k) {
    for (int j = 0; j < 10; ++j) Tn[j] = (j ? 2.0 * Tc[j - 1] : 0.0) - Tp[j];
    for (int j = 0; j < 10; ++j) am[j] += c[k] * Tn[j];
    std::memcpy(Tp, Tc, sizeof Tp);
    std::memcpy(Tc, Tn, sizeof Tc);
  }
  Coefs cf;
  for (int j = 0; j < 10; ++j) cf.a[j] = (float)am[j];
  cf.m = (float)m;
  cf.invr = (float)(1.0 / r);

  spdlog64<<<nb, 256, 0, stream>>>(A, O, cf);
}

// Round 6
// 59.969 us; speedup vs baseline: 5.0340x; 1.0375x over previous
//
#include <hip/hip_runtime.h>
#include <cmath>
#include <cstring>

// SPD log(A), 8192 64x64 SPD matrices.
// Degree-9 Chebyshev poly on [0.5,6.0] in Y=(A-mI)/r, Paterson-Stockmeyer:
//   P2=Y*Y, P3=Y*P2, R1=a9*P3+B2, R2=P3*R1+B1, out=P3*R2+B0.
// Round 6 (LDS-throughput attack): 2 waves per matrix (B-fragment re-reads
// halved), block = 256 thr = 2 matrices, 80KB LDS -> 2 blocks/CU (16 waves).
// Epilogue Y/P2 operands hoisted to registers (read once). P2 uses one-sided
// Yl correction (dropped Yh*Yl term ~6e-4 final error, budget 1.5e-2).
// All matrices are polynomials in Y => symmetric => A- and B-fragments both
// read as row slices; product stores go transposed. XOR-swizzled LDS.

typedef _Float16 half8 __attribute__((ext_vector_type(8)));
typedef _Float16 half4 __attribute__((ext_vector_type(4)));
typedef float f32x4 __attribute__((ext_vector_type(4)));

struct Coefs { float a[10]; float m, invr; };

#define PL_YH 0
#define PL_YL 8192
#define PL_P2 16384
#define PL_P3 24576
#define PL_R1 32768
#define PL_R2 PL_YL            /* YL dead after P3 stage */
#define MAT_LDS 40960

__device__ __forceinline__ int swz(int row, int bytecol) {
  return row * 128 + (bytecol ^ ((row & 7) << 4));
}

__device__ __forceinline__ half8 read_frag(const char* lds, int plane,
                                           int band, int s, int lane) {
  int row = band * 16 + (lane & 15);
  int bc = s * 64 + ((lane >> 4) << 4);
  return *(const half8*)(lds + plane + swz(row, bc));
}

#define MFMA16(a, b, c) __builtin_amdgcn_mfma_f32_16x16x32_f16((a), (b), (c), 0, 0, 0)

__global__ __launch_bounds__(256, 4) void spdlog64(const float* __restrict__ A,
                                                   float* __restrict__ O,
                                                   Coefs cf) {
  __shared__ __align__(16) char lds_all[2 * MAT_LDS];
  const int t = threadIdx.x;
  const int lane = t & 63;
  const int sw = (t >> 6) & 1;   // strip within matrix: 16-row bands {2sw, 2sw+1}
  const int im = t >> 7;         // which matrix of the block's pair
  char* lds = lds_all + im * MAT_LDS;
  const size_t gmat = (size_t)blockIdx.x * 2 + im;   // grid = nb/2 (nb even)
  const float* Ab = A + gmat * 4096;
  float* Ob = O + gmat * 4096;
  const int t2 = t & 127;        // thread index within the matrix's 2-wave team

  // ---- build Y = (A - m I)*invr, split f16 hi (RTNE) + residual ----
  #pragma unroll
  for (int i = 0; i < 8; ++i) {
    int q = t2 + 128 * i;                 // float4 index 0..1023
    float4 v = ((const float4*)Ab)[q];
    int e = q << 2, row = e >> 6, col = e & 63;
    float x[4];
    x[0] = (v.x - (col + 0 == row ? cf.m : 0.f)) * cf.invr;
    x[1] = (v.y - (col + 1 == row ? cf.m : 0.f)) * cf.invr;
    x[2] = (v.z - (col + 2 == row ? cf.m : 0.f)) * cf.invr;
    x[3] = (v.w - (col + 3 == row ? cf.m : 0.f)) * cf.invr;
    half4 h, l;
    #pragma unroll
    for (int j = 0; j < 4; ++j) {
      h[j] = (_Float16)x[j];
      l[j] = (_Float16)(x[j] - (float)h[j]);
    }
    int off = swz(row, col * 2);
    *(half4*)(lds + PL_YH + off) = h;
    *(half4*)(lds + PL_YL + off) = l;
  }
  __syncthreads();                        // barrier 1

  f32x4 acc[2][4];

  // tile geometry for this thread: tile (bi,f) covers
  // rows r0..r0+3 (r0 = band*16 + (lane>>4)*4), col c = f*16 + (lane&15);
  // transposed store/epi offset = swz(c, r0*2).
  const int r0b = ((lane >> 4) << 2);

  // ---- P2 = Yh*Yh + Yl*Yh (one-sided correction) ----
  #pragma unroll
  for (int bi = 0; bi < 2; ++bi)
    #pragma unroll
    for (int f = 0; f < 4; ++f) acc[bi][f] = (f32x4)0.f;
  #pragma unroll
  for (int s = 0; s < 2; ++s) {
    half8 Bh[4];
    #pragma unroll
    for (int f = 0; f < 4; ++f) Bh[f] = read_frag(lds, PL_YH, f, s, lane);
    #pragma unroll
    for (int bi = 0; bi < 2; ++bi) {
      half8 Ah = read_frag(lds, PL_YH, 2 * sw + bi, s, lane);
      half8 Al = read_frag(lds, PL_YL, 2 * sw + bi, s, lane);
      #pragma unroll
      for (int f = 0; f < 4; ++f) {
        acc[bi][f] = MFMA16(Ah, Bh[f], acc[bi][f]);
        acc[bi][f] = MFMA16(Al, Bh[f], acc[bi][f]);
      }
    }
  }
  #pragma unroll
  for (int bi = 0; bi < 2; ++bi)
    #pragma unroll
    for (int f = 0; f < 4; ++f) {
      int r0 = (2 * sw + bi) * 16 + r0b;
      int c = f * 16 + (lane & 15);
      half4 p = {(_Float16)acc[bi][f][0], (_Float16)acc[bi][f][1],
                 (_Float16)acc[bi][f][2], (_Float16)acc[bi][f][3]};
      *(half4*)(lds + PL_P2 + swz(c, r0 * 2)) = p;
    }
  __syncthreads();                        // barrier 2

  // ---- hoist epilogue operands: Y, P2 at each tile's transposed spot ----
  half4 yv[2][4], pv[2][4];
  #pragma unroll
  for (int bi = 0; bi < 2; ++bi)
    #pragma unroll
    for (int f = 0; f < 4; ++f) {
      int r0 = (2 * sw + bi) * 16 + r0b;
      int c = f * 16 + (lane & 15);
      int off = swz(c, r0 * 2);
      yv[bi][f] = *(const half4*)(lds + PL_YH + off);
      pv[bi][f] = *(const half4*)(lds + PL_P2 + off);
    }

  // ---- P3 = (Yh+Yl)*P2, fused R1 = a9*P3 + a6 I + a7 Y + a8 P2 ----
  #pragma unroll
  for (int bi = 0; bi < 2; ++bi)
    #pragma unroll
    for (int f = 0; f < 4; ++f) acc[bi][f] = (f32x4)0.f;
  #pragma unroll
  for (int s = 0; s < 2; ++s) {
    half8 Bp[4];
    #pragma unroll
    for (int f = 0; f < 4; ++f) Bp[f] = read_frag(lds, PL_P2, f, s, lane);
    #pragma unroll
    for (int bi = 0; bi < 2; ++bi) {
      half8 Ah = read_frag(lds, PL_YH, 2 * sw + bi, s, lane);
      half8 Al = read_frag(lds, PL_YL, 2 * sw + bi, s, lane);
      #pragma unroll
      for (int f = 0; f < 4; ++f) {
        acc[bi][f] = MFMA16(Ah, Bp[f], acc[bi][f]);
        acc[bi][f] = MFMA16(Al, Bp[f], acc[bi][f]);
      }
    }
  }
  #pragma unroll
  for (int bi = 0; bi < 2; ++bi)
    #pragma unroll
    for (int f = 0; f < 4; ++f) {
      int r0 = (2 * sw + bi) * 16 + r0b;
      int c = f * 16 + (lane & 15);
      int off = swz(c, r0 * 2);
      half4 p3, r1;
      #pragma unroll
      for (int j = 0; j < 4; ++j) {
        p3[j] = (_Float16)acc[bi][f][j];
        float rv = cf.a[9] * acc[bi][f][j] + cf.a[7] * (float)yv[bi][f][j] +
                   cf.a[8] * (float)pv[bi][f][j];
        if (r0 + j == c) rv += cf.a[6];
        r1[j] = (_Float16)rv;
      }
      *(half4*)(lds + PL_P3 + off) = p3;
      *(half4*)(lds + PL_R1 + off) = r1;
    }
  __syncthreads();                        // barrier 3

  // ---- R2 = P3*R1 + (a3 I + a4 Y + a5 P2) -> stored into YL slot ----
  #pragma unroll
  for (int bi = 0; bi < 2; ++bi)
    #pragma unroll
    for (int f = 0; f < 4; ++f) acc[bi][f] = (f32x4)0.f;
  #pragma unroll
  for (int s = 0; s < 2; ++s) {
    half8 Br[4];
    #pragma unroll
    for (int f = 0; f < 4; ++f) Br[f] = read_frag(lds, PL_R1, f, s, lane);
    #pragma unroll
    for (int bi = 0; bi < 2; ++bi) {
      half8 Ap = read_frag(lds, PL_P3, 2 * sw + bi, s, lane);
      #pragma unroll
      for (int f = 0; f < 4; ++f) acc[bi][f] = MFMA16(Ap, Br[f], acc[bi][f]);
    }
  }
  #pragma unroll
  for (int bi = 0; bi < 2; ++bi)
    #pragma unroll
    for (int f = 0; f < 4; ++f) {
      int r0 = (2 * sw + bi) * 16 + r0b;
      int c = f * 16 + (lane & 15);
      half4 r2;
      #pragma unroll
      for (int j = 0; j < 4; ++j) {
        float v = acc[bi][f][j] + cf.a[4] * (float)yv[bi][f][j] +
                  cf.a[5] * (float)pv[bi][f][j];
        if (r0 + j == c) v += cf.a[3];
        r2[j] = (_Float16)v;
      }
      *(half4*)(lds + PL_R2 + swz(c, r0 * 2)) = r2;
    }
  __syncthreads();                        // barrier 4

  // ---- out = P3*R2 + (a0 I + a1 Y + a2 P2) ----
  #pragma unroll
  for (int bi = 0; bi < 2; ++bi)
    #pragma unroll
    for (int f = 0; f < 4; ++f) acc[bi][f] = (f32x4)0.f;
  #pragma unroll
  for (int s = 0; s < 2; ++s) {
    half8 Br[4];
    #pragma unroll
    for (int f = 0; f < 4; ++f) Br[f] = read_frag(lds, PL_R2, f, s, lane);
    #pragma unroll
    for (int bi = 0; bi < 2; ++bi) {
      half8 Ap = read_frag(lds, PL_P3, 2 * sw + bi, s, lane);
      #pragma unroll
      for (int f = 0; f < 4; ++f) acc[bi][f] = MFMA16(Ap, Br[f], acc[bi][f]);
    }
  }
  #pragma unroll
  for (int bi = 0; bi < 2; ++bi)
    #pragma unroll
    for (int f = 0; f < 4; ++f) {
      int r0 = (2 * sw + bi) * 16 + r0b;
      int c = f * 16 + (lane & 15);
      float4 o;
      float* op = &o.x;
      #pragma unroll
      for (int j = 0; j < 4; ++j) {
        float v = acc[bi][f][j] + cf.a[1] * (float)yv[bi][f][j] +
                  cf.a[2] * (float)pv[bi][f][j];
        if (r0 + j == c) v += cf.a[0];
        op[j] = v;
      }
      *(float4*)(Ob + (size_t)c * 64 + r0) = o;   // transposed (symmetric)
    }
}

extern "C" void kernel_launch(void* const* d_in, const int* in_sizes, int n_in,
                              void* d_out, int out_size, void* d_ws, size_t ws_size,
                              hipStream_t stream) {
  (void)n_in; (void)out_size; (void)d_ws; (void)ws_size;
  const float* A = (const float*)d_in[0];
  float* O = (float*)d_out;
  const int nb = in_sizes[0] / 4096;      // 8192 (even)

  // Chebyshev series of log(x) on [lo,hi], degree 9, closed form:
  // x = m(1 + rho t); log = (log m - log(1+z^2)) + 2*sum (-1)^{k+1} z^k/k T_k(t)
  const double lo = 0.5, hi = 6.0;
  const double m = 0.5 * (lo + hi), r = 0.5 * (hi - lo), rho = r / m;
  const double sq = std::sqrt(1.0 - rho * rho);
  const double z = (1.0 - sq) / rho;
  const int D = 9;
  double c[10];
  c[0] = std::log(m) - std::log1p(z * z);
  double zk = z;
  for (int k = 1; k <= D; ++k) {
    c[k] = 2.0 * ((k & 1) ? 1.0 : -1.0) * zk / (double)k;
    zk *= z;
  }
  // Chebyshev -> monomial in t
  double Tp[10] = {0}, Tc[10] = {0}, Tn[10];
  double am[10] = {0};
  Tp[0] = 1.0;
  am[0] += c[0];
  Tc[1] = 1.0;
  am[1] += c[1];
  for (int k = 2; k <= D; ++k) {
    for (int j = 0; j < 10; ++j) Tn[j] = (j ? 2.0 * Tc[j - 1] : 0.0) - Tp[j];
    for (int j = 0; j < 10; ++j) am[j] += c[k] * Tn[j];
    std::memcpy(Tp, Tc, sizeof Tp);
    std::memcpy(Tc, Tn, sizeof Tc);
  }
  Coefs cf;
  for (int j = 0; j < 10; ++j) cf.a[j] = (float)am[j];
  cf.m = (float)m;
  cf.invr = (float)(1.0 / r);

  spdlog64<<<nb / 2, 256, 0, stream>>>(A, O, cf);
}

// Round 7
// 46.630 us; speedup vs baseline: 6.4740x; 1.2860x over previous
//
#include <hip/hip_runtime.h>
#include <cmath>
#include <cstring>

// SPD log(A), 8192 64x64 SPD matrices.
// Degree-9 Chebyshev poly on [0.5,6.0] in Y=(A-mI)/r, Paterson-Stockmeyer:
//   P2=Y*Y, P3=Y*P2, R1=a9*P3+B2, R2=P3*R1+B1, out=P3*R2+B0.
// Round 7 (occupancy attack): pure-f16 Y (split dropped; p'(Y)-weighted f16
// rounding ~1.7e-3, budget 1.5e-2). 4 LDS planes = 32KB/matrix, one matrix
// per 256-thread block -> 5 blocks/CU (20 waves/CU). P2 epi operand (pv)
// taken from accumulator registers (no LDS read); R2 reuses the dead Y plane.
// All matrices are polynomials in Y => symmetric & commuting => A- and
// B-fragments both read as row slices; product stores go transposed.
// XOR-swizzled LDS throughout.

typedef _Float16 half8 __attribute__((ext_vector_type(8)));
typedef _Float16 half4 __attribute__((ext_vector_type(4)));
typedef float f32x4 __attribute__((ext_vector_type(4)));

struct Coefs { float a[10]; float m, invr; };

#define PL_Y  0
#define PL_P2 8192
#define PL_P3 16384
#define PL_R1 24576
#define PL_R2 PL_Y             /* Y plane dead after P3 stage */
#define LDS_BYTES 32768

__device__ __forceinline__ int swz(int row, int bytecol) {
  return row * 128 + (bytecol ^ ((row & 7) << 4));
}

__device__ __forceinline__ half8 read_frag(const char* lds, int plane,
                                           int band, int s, int lane) {
  int row = band * 16 + (lane & 15);
  int bc = s * 64 + ((lane >> 4) << 4);
  return *(const half8*)(lds + plane + swz(row, bc));
}

#define MFMA16(a, b, c) __builtin_amdgcn_mfma_f32_16x16x32_f16((a), (b), (c), 0, 0, 0)

__global__ __launch_bounds__(256, 5) void spdlog64(const float* __restrict__ A,
                                                   float* __restrict__ O,
                                                   Coefs cf) {
  __shared__ __align__(16) char lds[LDS_BYTES];
  const int t = threadIdx.x;
  const int lane = t & 63;
  const int w = t >> 6;               // band: 16 rows per wave
  const float* Ab = A + (size_t)blockIdx.x * 4096;
  float* Ob = O + (size_t)blockIdx.x * 4096;

  // ---- load A, form Y = (A - m I)*invr, f16 RTNE ----
  #pragma unroll
  for (int i = 0; i < 4; ++i) {
    int q = t + 256 * i;              // float4 index 0..1023
    float4 v = ((const float4*)Ab)[q];
    int row = q >> 4, col = (q & 15) << 2;
    half4 h;
    h[0] = (_Float16)((v.x - (col + 0 == row ? cf.m : 0.f)) * cf.invr);
    h[1] = (_Float16)((v.y - (col + 1 == row ? cf.m : 0.f)) * cf.invr);
    h[2] = (_Float16)((v.z - (col + 2 == row ? cf.m : 0.f)) * cf.invr);
    h[3] = (_Float16)((v.w - (col + 3 == row ? cf.m : 0.f)) * cf.invr);
    *(half4*)(lds + PL_Y + swz(row, col * 2)) = h;
  }
  __syncthreads();                    // barrier 1

  // tile geometry: tile f covers rows r0..r0+3, col c = f*16 + (lane&15);
  // transposed store/epi offset = swz(c, r0*2).
  const int r0 = w * 16 + ((lane >> 4) << 2);
  const int cB = lane & 15;

  f32x4 acc[4];
  half4 yv[4], pv[4];

  // ---- P2 = Y*Y; pv from acc regs; yv hoisted; store P2 transposed ----
  #pragma unroll
  for (int f = 0; f < 4; ++f) acc[f] = (f32x4)0.f;
  #pragma unroll
  for (int s = 0; s < 2; ++s) {
    half8 Av = read_frag(lds, PL_Y, w, s, lane);
    #pragma unroll
    for (int f = 0; f < 4; ++f) {
      half8 Bv = read_frag(lds, PL_Y, f, s, lane);
      acc[f] = MFMA16(Av, Bv, acc[f]);
    }
  }
  #pragma unroll
  for (int f = 0; f < 4; ++f) {
    int c = f * 16 + cB;
    int off = swz(c, r0 * 2);
    half4 p = {(_Float16)acc[f][0], (_Float16)acc[f][1],
               (_Float16)acc[f][2], (_Float16)acc[f][3]};
    *(half4*)(lds + PL_P2 + off) = p;
    pv[f] = p;
    yv[f] = *(const half4*)(lds + PL_Y + off);  // read-only this pass: no race
  }
  __syncthreads();                    // barrier 2

  // ---- P3 = Y*P2, fused R1 = a9*P3 + a6 I + a7 Y + a8 P2 ----
  #pragma unroll
  for (int f = 0; f < 4; ++f) acc[f] = (f32x4)0.f;
  #pragma unroll
  for (int s = 0; s < 2; ++s) {
    half8 Av = read_frag(lds, PL_Y, w, s, lane);
    #pragma unroll
    for (int f = 0; f < 4; ++f) {
      half8 Bv = read_frag(lds, PL_P2, f, s, lane);
      acc[f] = MFMA16(Av, Bv, acc[f]);
    }
  }
  #pragma unroll
  for (int f = 0; f < 4; ++f) {
    int c = f * 16 + cB;
    int off = swz(c, r0 * 2);
    half4 p3, r1;
    #pragma unroll
    for (int j = 0; j < 4; ++j) {
      p3[j] = (_Float16)acc[f][j];
      float rv = cf.a[9] * acc[f][j] + cf.a[7] * (float)yv[f][j] +
                 cf.a[8] * (float)pv[f][j];
      if (r0 + j == c) rv += cf.a[6];
      r1[j] = (_Float16)rv;
    }
    *(half4*)(lds + PL_P3 + off) = p3;
    *(half4*)(lds + PL_R1 + off) = r1;
  }
  __syncthreads();                    // barrier 3

  // ---- R2 = P3*R1 + (a3 I + a4 Y + a5 P2) -> stored into Y plane ----
  #pragma unroll
  for (int f = 0; f < 4; ++f) acc[f] = (f32x4)0.f;
  #pragma unroll
  for (int s = 0; s < 2; ++s) {
    half8 Av = read_frag(lds, PL_P3, w, s, lane);
    #pragma unroll
    for (int f = 0; f < 4; ++f) {
      half8 Bv = read_frag(lds, PL_R1, f, s, lane);
      acc[f] = MFMA16(Av, Bv, acc[f]);
    }
  }
  #pragma unroll
  for (int f = 0; f < 4; ++f) {
    int c = f * 16 + cB;
    half4 r2;
    #pragma unroll
    for (int j = 0; j < 4; ++j) {
      float v = acc[f][j] + cf.a[4] * (float)yv[f][j] +
                cf.a[5] * (float)pv[f][j];
      if (r0 + j == c) v += cf.a[3];
      r2[j] = (_Float16)v;
    }
    *(half4*)(lds + PL_R2 + swz(c, r0 * 2)) = r2;
  }
  __syncthreads();                    // barrier 4

  // ---- out = P3*R2 + (a0 I + a1 Y + a2 P2) ----
  #pragma unroll
  for (int f = 0; f < 4; ++f) acc[f] = (f32x4)0.f;
  #pragma unroll
  for (int s = 0; s < 2; ++s) {
    half8 Av = read_frag(lds, PL_P3, w, s, lane);
    #pragma unroll
    for (int f = 0; f < 4; ++f) {
      half8 Bv = read_frag(lds, PL_R2, f, s, lane);
      acc[f] = MFMA16(Av, Bv, acc[f]);
    }
  }
  #pragma unroll
  for (int f = 0; f < 4; ++f) {
    int c = f * 16 + cB;
    float4 o;
    float* op = &o.x;
    #pragma unroll
    for (int j = 0; j < 4; ++j) {
      float v = acc[f][j] + cf.a[1] * (float)yv[f][j] +
                cf.a[2] * (float)pv[f][j];
      if (r0 + j == c) v += cf.a[0];
      op[j] = v;
    }
    *(float4*)(Ob + (size_t)c * 64 + r0) = o;   // transposed (symmetric)
  }
}

extern "C" void kernel_launch(void* const* d_in, const int* in_sizes, int n_in,
                              void* d_out, int out_size, void* d_ws, size_t ws_size,
                              hipStream_t stream) {
  (void)n_in; (void)out_size; (void)d_ws; (void)ws_size;
  const float* A = (const float*)d_in[0];
  float* O = (float*)d_out;
  const int nb = in_sizes[0] / 4096;

  // Chebyshev series of log(x) on [lo,hi], degree 9, closed form:
  // x = m(1 + rho t); log = (log m - log(1+z^2)) + 2*sum (-1)^{k+1} z^k/k T_k(t)
  const double lo = 0.5, hi = 6.0;
  const double m = 0.5 * (lo + hi), r = 0.5 * (hi - lo), rho = r / m;
  const double sq = std::sqrt(1.0 - rho * rho);
  const double z = (1.0 - sq) / rho;
  const int D = 9;
  double c[10];
  c[0] = std::log(m) - std::log1p(z * z);
  double zk = z;
  for (int k = 1; k <= D; ++k) {
    c[k] = 2.0 * ((k & 1) ? 1.0 : -1.0) * zk / (double)k;
    zk *= z;
  }
  // Chebyshev -> monomial in t
  double Tp[10] = {0}, Tc[10] = {0}, Tn[10];
  double am[10] = {0};
  Tp[0] = 1.0;
  am[0] += c[0];
  Tc[1] = 1.0;
  am[1] += c[1];
  for (int k = 2; k <= D; ++k) {
    for (int j = 0; j < 10; ++j) Tn[j] = (j ? 2.0 * Tc[j - 1] : 0.0) - Tp[j];
    for (int j = 0; j < 10; ++j) am[j] += c[k] * Tn[j];
    std::memcpy(Tp, Tc, sizeof Tp);
    std::memcpy(Tc, Tn, sizeof Tc);
  }
  Coefs cf;
  for (int j = 0; j < 10; ++j) cf.a[j] = (float)am[j];
  cf.m = (float)m;
  cf.invr = (float)(1.0 / r);

  spdlog64<<<nb, 256, 0, stream>>>(A, O, cf);
}

// Round 8
// 45.933 us; speedup vs baseline: 6.5723x; 1.0152x over previous
//
#include <hip/hip_runtime.h>
#include <cmath>
#include <cstring>

// SPD log(A), 8192 64x64 SPD matrices.
// Round 8: degree-6 Chebyshev poly on [0.5,5.8] in Y=(A-mI)/r, 3 matmuls:
//   P2=Y*Y, P3=Y*P2 (fused R1 = a6 P3 + a5 P2 + a4 Y + a3 I),
//   out = P3*R1 + (a2 P2 + a1 Y + a0 I).
// Error budget: trunc ~6-9e-3 + f16 noise ~4e-3 < 1.52e-2 threshold.
// Pure-f16 operand storage; f32 MFMA accumulate; epilogue operands (yv,pv)
// register-hoisted. 4 LDS planes = 32KB -> 5 blocks/CU (20 waves/CU).
// All matrices are polynomials in Y => symmetric => A- and B-fragments both
// read as row slices; product stores go transposed. XOR-swizzled LDS.

typedef _Float16 half8 __attribute__((ext_vector_type(8)));
typedef _Float16 half4 __attribute__((ext_vector_type(4)));
typedef float f32x4 __attribute__((ext_vector_type(4)));

struct Coefs { float a[8]; float m, invr; };

#define PL_Y  0
#define PL_P2 8192
#define PL_P3 16384
#define PL_R1 24576
#define LDS_BYTES 32768

__device__ __forceinline__ int swz(int row, int bytecol) {
  return row * 128 + (bytecol ^ ((row & 7) << 4));
}

__device__ __forceinline__ half8 read_frag(const char* lds, int plane,
                                           int band, int s, int lane) {
  int row = band * 16 + (lane & 15);
  int bc = s * 64 + ((lane >> 4) << 4);
  return *(const half8*)(lds + plane + swz(row, bc));
}

#define MFMA16(a, b, c) __builtin_amdgcn_mfma_f32_16x16x32_f16((a), (b), (c), 0, 0, 0)

__global__ __launch_bounds__(256, 5) void spdlog64(const float* __restrict__ A,
                                                   float* __restrict__ O,
                                                   Coefs cf) {
  __shared__ __align__(16) char lds[LDS_BYTES];
  const int t = threadIdx.x;
  const int lane = t & 63;
  const int w = t >> 6;               // band: 16 rows per wave
  const float* Ab = A + (size_t)blockIdx.x * 4096;
  float* Ob = O + (size_t)blockIdx.x * 4096;

  // ---- load A, form Y = (A - m I)*invr, f16 RTNE ----
  #pragma unroll
  for (int i = 0; i < 4; ++i) {
    int q = t + 256 * i;              // float4 index 0..1023
    float4 v = ((const float4*)Ab)[q];
    int row = q >> 4, col = (q & 15) << 2;
    half4 h;
    h[0] = (_Float16)((v.x - (col + 0 == row ? cf.m : 0.f)) * cf.invr);
    h[1] = (_Float16)((v.y - (col + 1 == row ? cf.m : 0.f)) * cf.invr);
    h[2] = (_Float16)((v.z - (col + 2 == row ? cf.m : 0.f)) * cf.invr);
    h[3] = (_Float16)((v.w - (col + 3 == row ? cf.m : 0.f)) * cf.invr);
    *(half4*)(lds + PL_Y + swz(row, col * 2)) = h;
  }
  __syncthreads();                    // barrier 1

  // tile geometry: tile f covers rows r0..r0+3, col c = f*16 + (lane&15);
  // transposed store/epi offset = swz(c, r0*2).
  const int r0 = w * 16 + ((lane >> 4) << 2);
  const int cB = lane & 15;

  f32x4 acc[4];
  half4 yv[4], pv[4];

  // ---- P2 = Y*Y; pv from acc regs; yv hoisted; store P2 transposed ----
  #pragma unroll
  for (int f = 0; f < 4; ++f) acc[f] = (f32x4)0.f;
  #pragma unroll
  for (int s = 0; s < 2; ++s) {
    half8 Av = read_frag(lds, PL_Y, w, s, lane);
    #pragma unroll
    for (int f = 0; f < 4; ++f) {
      half8 Bv = read_frag(lds, PL_Y, f, s, lane);
      acc[f] = MFMA16(Av, Bv, acc[f]);
    }
  }
  #pragma unroll
  for (int f = 0; f < 4; ++f) {
    int c = f * 16 + cB;
    int off = swz(c, r0 * 2);
    half4 p = {(_Float16)acc[f][0], (_Float16)acc[f][1],
               (_Float16)acc[f][2], (_Float16)acc[f][3]};
    *(half4*)(lds + PL_P2 + off) = p;
    pv[f] = p;
    yv[f] = *(const half4*)(lds + PL_Y + off);  // read-only this pass: no race
  }
  __syncthreads();                    // barrier 2

  // ---- P3 = Y*P2, fused R1 = a6*P3 + a5*P2 + a4*Y + a3*I ----
  #pragma unroll
  for (int f = 0; f < 4; ++f) acc[f] = (f32x4)0.f;
  #pragma unroll
  for (int s = 0; s < 2; ++s) {
    half8 Av = read_frag(lds, PL_Y, w, s, lane);
    #pragma unroll
    for (int f = 0; f < 4; ++f) {
      half8 Bv = read_frag(lds, PL_P2, f, s, lane);
      acc[f] = MFMA16(Av, Bv, acc[f]);
    }
  }
  #pragma unroll
  for (int f = 0; f < 4; ++f) {
    int c = f * 16 + cB;
    int off = swz(c, r0 * 2);
    half4 p3, r1;
    #pragma unroll
    for (int j = 0; j < 4; ++j) {
      p3[j] = (_Float16)acc[f][j];
      float rv = cf.a[6] * acc[f][j] + cf.a[4] * (float)yv[f][j] +
                 cf.a[5] * (float)pv[f][j];
      if (r0 + j == c) rv += cf.a[3];
      r1[j] = (_Float16)rv;
    }
    *(half4*)(lds + PL_P3 + off) = p3;
    *(half4*)(lds + PL_R1 + off) = r1;
  }
  __syncthreads();                    // barrier 3

  // ---- out = P3*R1 + (a0 I + a1 Y + a2 P2) -> global ----
  #pragma unroll
  for (int f = 0; f < 4; ++f) acc[f] = (f32x4)0.f;
  #pragma unroll
  for (int s = 0; s < 2; ++s) {
    half8 Av = read_frag(lds, PL_P3, w, s, lane);
    #pragma unroll
    for (int f = 0; f < 4; ++f) {
      half8 Bv = read_frag(lds, PL_R1, f, s, lane);
      acc[f] = MFMA16(Av, Bv, acc[f]);
    }
  }
  #pragma unroll
  for (int f = 0; f < 4; ++f) {
    int c = f * 16 + cB;
    float4 o;
    float* op = &o.x;
    #pragma unroll
    for (int j = 0; j < 4; ++j) {
      float v = acc[f][j] + cf.a[1] * (float)yv[f][j] +
                cf.a[2] * (float)pv[f][j];
      if (r0 + j == c) v += cf.a[0];
      op[j] = v;
    }
    *(float4*)(Ob + (size_t)c * 64 + r0) = o;   // transposed (symmetric)
  }
}

extern "C" void kernel_launch(void* const* d_in, const int* in_sizes, int n_in,
                              void* d_out, int out_size, void* d_ws, size_t ws_size,
                              hipStream_t stream) {
  (void)n_in; (void)out_size; (void)d_ws; (void)ws_size;
  const float* A = (const float*)d_in[0];
  float* O = (float*)d_out;
  const int nb = in_sizes[0] / 4096;

  // Chebyshev series of log(x) on [lo,hi], degree 6, closed form:
  // x = m(1 + rho t); log = (log m - log(1+z^2)) + 2*sum (-1)^{k+1} z^k/k T_k(t)
  const double lo = 0.5, hi = 5.8;
  const double m = 0.5 * (lo + hi), r = 0.5 * (hi - lo), rho = r / m;
  const double sq = std::sqrt(1.0 - rho * rho);
  const double z = (1.0 - sq) / rho;
  const int D = 6;
  double c[8];
  c[0] = std::log(m) - std::log1p(z * z);
  double zk = z;
  for (int k = 1; k <= D; ++k) {
    c[k] = 2.0 * ((k & 1) ? 1.0 : -1.0) * zk / (double)k;
    zk *= z;
  }
  // Chebyshev -> monomial in t
  double Tp[8] = {0}, Tc[8] = {0}, Tn[8];
  double am[8] = {0};
  Tp[0] = 1.0;
  am[0] += c[0];
  Tc[1] = 1.0;
  am[1] += c[1];
  for (int k = 2; k <= D; ++k) {
    for (int j = 0; j < 8; ++j) Tn[j] = (j ? 2.0 * Tc[j - 1] : 0.0) - Tp[j];
    for (int j = 0; j < 8; ++j) am[j] += c[k] * Tn[j];
    std::memcpy(Tp, Tc, sizeof Tp);
    std::memcpy(Tc, Tn, sizeof Tc);
  }
  Coefs cf;
  for (int j = 0; j < 8; ++j) cf.a[j] = (float)am[j];
  cf.m = (float)m;
  cf.invr = (float)(1.0 / r);

  spdlog64<<<nb, 256, 0, stream>>>(A, O, cf);
}